// Round 6
// baseline (15219.176 us; speedup 1.0000x reference)
//
#include <hip/hip_runtime.h>
#include <stdint.h>

// GRU scan, persistent cooperative kernel, round 6.
// Round 5 + split-half software pipeline across the cluster barrier:
//   phase1 (rows 0-31) -> gates+stores lo -> post flagLo -> phase2 (rows 32-63)
//   -> gates+stores hi -> post flagHi. Consumers poll flagLo(t), stage lo, and
//   run phase1 while producers are still in phase2 -> exchange latency of each
//   half hides under compute of the other half.
// Coherence discipline unchanged from round 5 (proven): write-through h stores
// (RELAXED/AGENT -> sc0 sc1), no-allocate read-through staging (aux=17),
// relaxed flag add after vmcnt(0)+barrier, relaxed polls, no fences.

#define NB 256
#define NT 128
#define TB 1024
#define TT 2048
#define II 12
#define HH 512
#define GBLK 16
#define ROWS 64
#define NCL 16

#define HTILE_B (ROWS * HH * 2)               // 64 KiB per cluster per buffer
#define HBUF_B  ((size_t)NCL * HTILE_B)       // 1 MiB per buffer
#define BAR_OFF ((size_t)2 * HBUF_B)
#define WS_USED (BAR_OFF + 2048)              // flagLo[16] + flagHi[16], 64B spaced

#define LDS_W_B   (64 * 1024)                 // 64 KiB weights (r,z gates)
#define LDSB      (LDS_W_B + ROWS * 1024)     // 131072 = 128 KiB

#define GAS __attribute__((address_space(1)))
#define LAS __attribute__((address_space(3)))

typedef _Float16 half8 __attribute__((ext_vector_type(8)));
typedef float    f32x4 __attribute__((ext_vector_type(4)));

static __device__ __forceinline__ float fast_sigmoid(float x) {
  float e = exp2f(-1.44269504f * x);
  return __builtin_amdgcn_rcpf(1.0f + e);
}
static __device__ __forceinline__ float fast_tanh(float x) {
  float e = exp2f(2.88539008f * x);           // exp(2x)
  return 1.0f - 2.0f * __builtin_amdgcn_rcpf(1.0f + e);
}

// All lanes poll (same address -> broadcast load); per-wave, no block sync.
static __device__ __forceinline__ void wait_flag(unsigned* p, unsigned tgt,
                                                 int* dead) {
  long spin = 0;
  while (!*dead &&
         __hip_atomic_load(p, __ATOMIC_RELAXED, __HIP_MEMORY_SCOPE_AGENT) < tgt)
    if (++spin > (1L << 24)) *dead = 1;
}

__global__ void __launch_bounds__(NT, 1)
gru_persistent(const float* __restrict__ hist,
               const float* __restrict__ w_ih,
               const float* __restrict__ w_hh,
               const float* __restrict__ w_out,
               const float* __restrict__ b_out,
               float* __restrict__ out,
               uint8_t* __restrict__ ws)
{
  extern __shared__ char smem[];
  char* ldsW = smem;
  char* ldsA = smem + LDS_W_B;
  const int bid = blockIdx.x;
  const int c   = bid & 15;          // cluster
  const int g   = bid >> 4;          // block within cluster
  const int tid = threadIdx.x;
  const int wv  = tid >> 6;
  const int l   = tid & 63;
  const int l15 = l & 15;
  const int l4  = l >> 4;
  const int crb = c * ROWS;
  unsigned* barLo = (unsigned*)(ws + BAR_OFF) + c * 16;          // 64B spaced
  unsigned* barHi = (unsigned*)(ws + BAR_OFF + 1024) + c * 16;

  // ---- W_hh (r,z) LDS fill: local row j = 32*wv_j + 16*gate + pl
  for (int idx = tid; idx < 64 * 64; idx += NT) {
    const int j   = idx >> 6;
    const int k8  = (idx & 63) * 8;
    const int wvj = j >> 5;
    const int gt  = (j >> 4) & 1;
    const int pl  = j & 15;
    const int R   = gt * HH + g * 32 + wvj * 16 + pl;
    half8 v;
#pragma unroll
    for (int i = 0; i < 8; ++i) v[i] = (_Float16)w_hh[(size_t)R * HH + k8 + i];
    *(half8*)(ldsW + j * 1024 + ((2 * k8) ^ ((j & 7) << 4))) = v;
  }

  // ---- n-gate W_hh slice in registers (statically indexed)
  half8 wn[16];
  {
    const int Rn = 2 * HH + g * 32 + wv * 16 + l15;
#pragma unroll
    for (int ks = 0; ks < 16; ++ks)
#pragma unroll
      for (int i = 0; i < 8; ++i)
        wn[ks][i] = (_Float16)w_hh[(size_t)Rn * HH + ks * 32 + l4 * 8 + i];
  }

  // ---- w_ih register B-fragments for gates r,z,n (K window = x cols 0..31)
  half8 wih[3];
#pragma unroll
  for (int gt = 0; gt < 3; ++gt) {
    const int R = gt * HH + g * 32 + wv * 16 + l15;
#pragma unroll
    for (int i = 0; i < 8; ++i) {
      const int k = l4 * 8 + i;
      wih[gt][i] = (_Float16)((k < II) ? w_ih[R * II + k] : 0.0f);
    }
  }

  // ---- w_out in registers
  const int jj = (l >> 4) & 1;
  float wor[32];
#pragma unroll
  for (int i = 0; i < 32; ++i) wor[i] = w_out[jj * HH + l15 * 32 + i];
  const float bo = b_out[jj];

  float hprev[4][4];
#pragma unroll
  for (int mt = 0; mt < 4; ++mt)
#pragma unroll
    for (int q = 0; q < 4; ++q) hprev[mt][q] = 0.0f;

  const int pcol = g * 32 + wv * 16 + l15;
  int deadlock = 0;

  __syncthreads();   // W LDS ready

  for (int t = 0; t <= TT; ++t) {
    const uint8_t* hsrc = ws + ((t & 1) ? HBUF_B : 0) + (size_t)c * HTILE_B;
    uint8_t*       hdst = ws + ((t & 1) ? 0 : HBUF_B) + (size_t)c * HTILE_B;

    // ---- wait lo half of h(t), issue x + lo staging
    if (t > 0) wait_flag(barLo, (unsigned)(GBLK * t), &deadlock);

    f32x4 xa[4], xb4[4];
    if (t < TT) {
#pragma unroll
      for (int mt = 0; mt < 4; ++mt) {
        const float* xp = hist + (size_t)(crb + mt * 16 + l15) * (TT * II) + (size_t)t * II;
        xa[mt]  = (f32x4){0.f, 0.f, 0.f, 0.f};
        xb4[mt] = (f32x4){0.f, 0.f, 0.f, 0.f};
        if (l4 == 0)      { xa[mt] = *(const f32x4*)xp; xb4[mt] = *(const f32x4*)(xp + 4); }
        else if (l4 == 1) { xa[mt] = *(const f32x4*)(xp + 8); }
      }
    }
    __builtin_amdgcn_sched_barrier(0);
#pragma unroll
    for (int it = 0; it < 16; ++it)          // rows 0-31 (first 32 KiB)
      __builtin_amdgcn_global_load_lds(
          (const GAS uint32_t*)(hsrc + it * 2048 + tid * 16),
          (LAS uint32_t*)(ldsA + it * 2048 + tid * 16), 16, 0, 17);
    __builtin_amdgcn_sched_barrier(0);

    // ---- wait hi half, issue hi staging
    if (t > 0) wait_flag(barHi, (unsigned)(GBLK * t), &deadlock);
#pragma unroll
    for (int it = 16; it < 32; ++it)         // rows 32-63
      __builtin_amdgcn_global_load_lds(
          (const GAS uint32_t*)(hsrc + it * 2048 + tid * 16),
          (LAS uint32_t*)(ldsA + it * 2048 + tid * 16), 16, 0, 17);
    __builtin_amdgcn_sched_barrier(0);

    asm volatile("s_waitcnt vmcnt(16)" ::: "memory");   // x + lo staged
    __builtin_amdgcn_s_barrier();
    __builtin_amdgcn_sched_barrier(0);

    f32x4 acc[4][3];
    f32x4 accin[4];
#pragma unroll
    for (int mt = 0; mt < 4; ++mt) {
      accin[mt] = (f32x4){0.f, 0.f, 0.f, 0.f};
#pragma unroll
      for (int nt = 0; nt < 3; ++nt) acc[mt][nt] = (f32x4){0.f, 0.f, 0.f, 0.f};
    }

    if (t < TT) {
      // x fragments + x MFMAs (all 4 mt; accin[2..3] carried into phase 2)
      half8 ax[4];
#pragma unroll
      for (int mt = 0; mt < 4; ++mt)
#pragma unroll
        for (int i = 0; i < 4; ++i) {
          ax[mt][i]     = (_Float16)xa[mt][i];
          ax[mt][4 + i] = (_Float16)xb4[mt][i];
        }
#pragma unroll
      for (int mt = 0; mt < 4; ++mt) {
        acc[mt][0] = __builtin_amdgcn_mfma_f32_16x16x32_f16(ax[mt], wih[0], acc[mt][0], 0, 0, 0);
        acc[mt][1] = __builtin_amdgcn_mfma_f32_16x16x32_f16(ax[mt], wih[1], acc[mt][1], 0, 0, 0);
        accin[mt]  = __builtin_amdgcn_mfma_f32_16x16x32_f16(ax[mt], wih[2], accin[mt], 0, 0, 0);
      }

      // ---- phase 1: rows 0-31 (mt = 0,1)
#pragma unroll
      for (int ks = 0; ks < 16; ++ks) {
        const int ko = (ks * 64 + l4 * 16) ^ ((l15 & 7) << 4);
        half8 a0 = *(const half8*)(ldsA + (0 * 16 + l15) * 1024 + ko);
        half8 a1 = *(const half8*)(ldsA + (1 * 16 + l15) * 1024 + ko);
        half8 b0 = *(const half8*)(ldsW + (wv * 32 + 0 * 16 + l15) * 1024 + ko);
        half8 b1 = *(const half8*)(ldsW + (wv * 32 + 1 * 16 + l15) * 1024 + ko);
        acc[0][0] = __builtin_amdgcn_mfma_f32_16x16x32_f16(a0, b0, acc[0][0], 0, 0, 0);
        acc[0][1] = __builtin_amdgcn_mfma_f32_16x16x32_f16(a0, b1, acc[0][1], 0, 0, 0);
        acc[0][2] = __builtin_amdgcn_mfma_f32_16x16x32_f16(a0, wn[ks], acc[0][2], 0, 0, 0);
        acc[1][0] = __builtin_amdgcn_mfma_f32_16x16x32_f16(a1, b0, acc[1][0], 0, 0, 0);
        acc[1][1] = __builtin_amdgcn_mfma_f32_16x16x32_f16(a1, b1, acc[1][1], 0, 0, 0);
        acc[1][2] = __builtin_amdgcn_mfma_f32_16x16x32_f16(a1, wn[ks], acc[1][2], 0, 0, 0);
      }

      // ---- gates + stores, rows 0-31 (write-through, pre-swizzled)
#pragma unroll
      for (int mt = 0; mt < 2; ++mt)
#pragma unroll
        for (int q = 0; q < 4; ++q) {
          const int m = mt * 16 + l4 * 4 + q;
          const float r  = fast_sigmoid(acc[mt][0][q]);
          const float z  = fast_sigmoid(acc[mt][1][q]);
          const float n  = fast_tanh(accin[mt][q] + r * acc[mt][2][q]);
          const float hn = (1.0f - z) * n + z * hprev[mt][q];
          hprev[mt][q] = hn;
          const unsigned short hu = __builtin_bit_cast(unsigned short, (_Float16)hn);
          __hip_atomic_store(
              (unsigned short*)(hdst + m * 1024 + ((pcol * 2) ^ ((m & 7) << 4))),
              hu, __ATOMIC_RELAXED, __HIP_MEMORY_SCOPE_AGENT);
        }
    }

    // drain lo stores (+ hi staging reads, needed for phase 2 / logits anyway)
    asm volatile("s_waitcnt vmcnt(0)" ::: "memory");
    __builtin_amdgcn_s_barrier();
    if (t < TT && tid == 0)
      __hip_atomic_fetch_add(barLo, 1u, __ATOMIC_RELAXED, __HIP_MEMORY_SCOPE_AGENT);

    // ---- logits for step t-1 from fully-staged h(t)
    if (t > 0) {
      const int rr   = 2 * wv + (l >> 5);
      const int lrow = g * 4 + rr;
      const int row  = crb + lrow;
      float s = 0.0f;
#pragma unroll
      for (int c8 = 0; c8 < 4; ++c8) {
        half8 hv = *(const half8*)(ldsA + lrow * 1024 +
                                   ((l15 * 64 + c8 * 16) ^ ((lrow & 7) << 4)));
#pragma unroll
        for (int i = 0; i < 8; ++i) s += (float)hv[i] * wor[c8 * 8 + i];
      }
#pragma unroll
      for (int off = 1; off < 16; off <<= 1) s += __shfl_xor(s, off);
      if (l15 == 0) out[((size_t)row * TT + (t - 1)) * 2 + jj] = s + bo;
    }
    if (t == TT) break;

    // ---- phase 2: rows 32-63 (mt = 2,3)
#pragma unroll
    for (int ks = 0; ks < 16; ++ks) {
      const int ko = (ks * 64 + l4 * 16) ^ ((l15 & 7) << 4);
      half8 a2 = *(const half8*)(ldsA + (2 * 16 + l15) * 1024 + ko);
      half8 a3 = *(const half8*)(ldsA + (3 * 16 + l15) * 1024 + ko);
      half8 b0 = *(const half8*)(ldsW + (wv * 32 + 0 * 16 + l15) * 1024 + ko);
      half8 b1 = *(const half8*)(ldsW + (wv * 32 + 1 * 16 + l15) * 1024 + ko);
      acc[2][0] = __builtin_amdgcn_mfma_f32_16x16x32_f16(a2, b0, acc[2][0], 0, 0, 0);
      acc[2][1] = __builtin_amdgcn_mfma_f32_16x16x32_f16(a2, b1, acc[2][1], 0, 0, 0);
      acc[2][2] = __builtin_amdgcn_mfma_f32_16x16x32_f16(a2, wn[ks], acc[2][2], 0, 0, 0);
      acc[3][0] = __builtin_amdgcn_mfma_f32_16x16x32_f16(a3, b0, acc[3][0], 0, 0, 0);
      acc[3][1] = __builtin_amdgcn_mfma_f32_16x16x32_f16(a3, b1, acc[3][1], 0, 0, 0);
      acc[3][2] = __builtin_amdgcn_mfma_f32_16x16x32_f16(a3, wn[ks], acc[3][2], 0, 0, 0);
    }

    // ---- gates + stores, rows 32-63
#pragma unroll
    for (int mt = 2; mt < 4; ++mt)
#pragma unroll
      for (int q = 0; q < 4; ++q) {
        const int m = mt * 16 + l4 * 4 + q;
        const float r  = fast_sigmoid(acc[mt][0][q]);
        const float z  = fast_sigmoid(acc[mt][1][q]);
        const float n  = fast_tanh(accin[mt][q] + r * acc[mt][2][q]);
        const float hn = (1.0f - z) * n + z * hprev[mt][q];
        hprev[mt][q] = hn;
        const unsigned short hu = __builtin_bit_cast(unsigned short, (_Float16)hn);
        __hip_atomic_store(
            (unsigned short*)(hdst + m * 1024 + ((pcol * 2) ^ ((m & 7) << 4))),
            hu, __ATOMIC_RELAXED, __HIP_MEMORY_SCOPE_AGENT);
      }

    asm volatile("s_waitcnt vmcnt(0)" ::: "memory");
    __builtin_amdgcn_s_barrier();
    if (tid == 0)
      __hip_atomic_fetch_add(barHi, 1u, __ATOMIC_RELAXED, __HIP_MEMORY_SCOPE_AGENT);
  }

  // ---- h_final from fp32 carried state
#pragma unroll
  for (int mt = 0; mt < 4; ++mt)
#pragma unroll
    for (int q = 0; q < 4; ++q) {
      const int m = mt * 16 + l4 * 4 + q;
      out[(size_t)TB * TT * 2 + (size_t)(crb + m) * HH + pcol] = hprev[mt][q];
    }
}

extern "C" void kernel_launch(void* const* d_in, const int* in_sizes, int n_in,
                              void* d_out, int out_size, void* d_ws, size_t ws_size,
                              hipStream_t stream) {
  (void)in_sizes; (void)n_in; (void)out_size;
  if (ws_size < WS_USED) return;

  const float* hist  = (const float*)d_in[0];
  const float* w_ih  = (const float*)d_in[1];
  const float* w_hh  = (const float*)d_in[2];
  const float* w_out = (const float*)d_in[3];
  const float* b_out = (const float*)d_in[4];
  float* out = (float*)d_out;
  uint8_t* ws = (uint8_t*)d_ws;

  hipFuncSetAttribute((const void*)gru_persistent,
                      hipFuncAttributeMaxDynamicSharedMemorySize, LDSB);
  hipMemsetAsync(d_ws, 0, WS_USED, stream);   // h0 = 0, flag counters

  void* args[] = {(void*)&hist, (void*)&w_ih, (void*)&w_hh, (void*)&w_out,
                  (void*)&b_out, (void*)&out, (void*)&ws};
  hipError_t e = hipLaunchCooperativeKernel((const void*)gru_persistent,
                                            dim3(NB), dim3(NT), args,
                                            (unsigned)LDSB, stream);
  if (e != hipSuccess) {
    // Fallback: plain launch. 256 blocks at 1/CU on 256 CUs co-reside; the
    // flag spin has a deadlock bail-out so this cannot hang.
    gru_persistent<<<dim3(NB), dim3(NT), LDSB, stream>>>(
        hist, w_ih, w_hh, w_out, b_out, out, ws);
  }
}

// Round 7
// 12669.665 us; speedup vs baseline: 1.2012x; 1.2012x over previous
//
#include <hip/hip_runtime.h>
#include <stdint.h>

// GRU scan, persistent cooperative kernel, round 7.
// Round 5 coherence discipline (write-through h stores RELAXED/AGENT, aux=17
// read-through staging, single relaxed flag per cluster, no fences) +
//  - x prefetched one step ahead into registers (removes per-step HBM latency
//    from the critical path; round 5/6 serialized an HBM round trip in the
//    vmcnt(16) wait every step)
//  - exact counted vmcnt: 32 staging + 12 x loads -> vmcnt(28)=lo staged,
//    after 8 lo stores vmcnt(20)=hi staged, vmcnt(0) only at step end
//  - store-drain hidden under logits (LDS+reg only) before the flag post
//  - single flag (round 6's lo/hi split regressed: extra barrier+poll+post)

#define NB 256
#define NT 128
#define TB 1024
#define TT 2048
#define II 12
#define HH 512
#define GBLK 16
#define ROWS 64
#define NCL 16

#define HTILE_B (ROWS * HH * 2)               // 64 KiB per cluster per buffer
#define HBUF_B  ((size_t)NCL * HTILE_B)       // 1 MiB per buffer
#define BAR_OFF ((size_t)2 * HBUF_B)
#define WS_USED (BAR_OFF + 1024)

#define LDS_W_B   (64 * 1024)                 // 64 KiB weights (r,z gates)
#define LDSB      (LDS_W_B + ROWS * 1024)     // 131072 = 128 KiB

#define GAS __attribute__((address_space(1)))
#define LAS __attribute__((address_space(3)))

typedef _Float16 half8 __attribute__((ext_vector_type(8)));
typedef float    f32x4 __attribute__((ext_vector_type(4)));

static __device__ __forceinline__ float fast_sigmoid(float x) {
  float e = exp2f(-1.44269504f * x);
  return __builtin_amdgcn_rcpf(1.0f + e);
}
static __device__ __forceinline__ float fast_tanh(float x) {
  float e = exp2f(2.88539008f * x);           // exp(2x)
  return 1.0f - 2.0f * __builtin_amdgcn_rcpf(1.0f + e);
}

// All lanes poll (same address -> broadcast load); per-wave, no block sync.
static __device__ __forceinline__ void wait_flag(unsigned* p, unsigned tgt,
                                                 int* dead) {
  long spin = 0;
  while (!*dead &&
         __hip_atomic_load(p, __ATOMIC_RELAXED, __HIP_MEMORY_SCOPE_AGENT) < tgt)
    if (++spin > (1L << 24)) *dead = 1;
}

__global__ void __launch_bounds__(NT, 1)
gru_persistent(const float* __restrict__ hist,
               const float* __restrict__ w_ih,
               const float* __restrict__ w_hh,
               const float* __restrict__ w_out,
               const float* __restrict__ b_out,
               float* __restrict__ out,
               uint8_t* __restrict__ ws)
{
  extern __shared__ char smem[];
  char* ldsW = smem;
  char* ldsA = smem + LDS_W_B;
  const int bid = blockIdx.x;
  const int c   = bid & 15;          // cluster
  const int g   = bid >> 4;          // block within cluster
  const int tid = threadIdx.x;
  const int wv  = tid >> 6;
  const int l   = tid & 63;
  const int l15 = l & 15;
  const int l4  = l >> 4;
  const int crb = c * ROWS;
  unsigned* bar = (unsigned*)(ws + BAR_OFF) + c * 16;    // 64B spaced

  // ---- W_hh (r,z) LDS fill: local row j = 32*wv_j + 16*gate + pl
  for (int idx = tid; idx < 64 * 64; idx += NT) {
    const int j   = idx >> 6;
    const int k8  = (idx & 63) * 8;
    const int wvj = j >> 5;
    const int gt  = (j >> 4) & 1;
    const int pl  = j & 15;
    const int R   = gt * HH + g * 32 + wvj * 16 + pl;
    half8 v;
#pragma unroll
    for (int i = 0; i < 8; ++i) v[i] = (_Float16)w_hh[(size_t)R * HH + k8 + i];
    *(half8*)(ldsW + j * 1024 + ((2 * k8) ^ ((j & 7) << 4))) = v;
  }

  // ---- n-gate W_hh slice in registers (statically indexed)
  half8 wn[16];
  {
    const int Rn = 2 * HH + g * 32 + wv * 16 + l15;
#pragma unroll
    for (int ks = 0; ks < 16; ++ks)
#pragma unroll
      for (int i = 0; i < 8; ++i)
        wn[ks][i] = (_Float16)w_hh[(size_t)Rn * HH + ks * 32 + l4 * 8 + i];
  }

  // ---- w_ih register B-fragments for gates r,z,n (K window = x cols 0..31)
  half8 wih[3];
#pragma unroll
  for (int gt = 0; gt < 3; ++gt) {
    const int R = gt * HH + g * 32 + wv * 16 + l15;
#pragma unroll
    for (int i = 0; i < 8; ++i) {
      const int k = l4 * 8 + i;
      wih[gt][i] = (_Float16)((k < II) ? w_ih[R * II + k] : 0.0f);
    }
  }

  // ---- w_out in registers
  const int jj = (l >> 4) & 1;
  float wor[32];
#pragma unroll
  for (int i = 0; i < 32; ++i) wor[i] = w_out[jj * HH + l15 * 32 + i];
  const float bo = b_out[jj];

  float hprev[4][4];
#pragma unroll
  for (int mt = 0; mt < 4; ++mt)
#pragma unroll
    for (int q = 0; q < 4; ++q) hprev[mt][q] = 0.0f;

  const int pcol = g * 32 + wv * 16 + l15;
  int deadlock = 0;

  // ---- x prologue: prefetch x(0). Lanes l4>=2 (and xn1 of l4==1) stay zero
  //      forever; in-loop only l4==0/1 lanes reload.
  f32x4 xn0[4], xn1[4];
#pragma unroll
  for (int mt = 0; mt < 4; ++mt) {
    xn0[mt] = (f32x4){0.f, 0.f, 0.f, 0.f};
    xn1[mt] = (f32x4){0.f, 0.f, 0.f, 0.f};
    const float* xp = hist + (size_t)(crb + mt * 16 + l15) * (TT * II);
    if (l4 == 0)      { xn0[mt] = *(const f32x4*)xp; xn1[mt] = *(const f32x4*)(xp + 4); }
    else if (l4 == 1) { xn0[mt] = *(const f32x4*)(xp + 8); }
  }

  __syncthreads();   // W LDS ready

  for (int t = 0; t < TT; ++t) {
    const uint8_t* hsrc = ws + ((t & 1) ? HBUF_B : 0) + (size_t)c * HTILE_B;
    uint8_t*       hdst = ws + ((t & 1) ? 0 : HBUF_B) + (size_t)c * HTILE_B;

    if (t > 0) wait_flag(bar, (unsigned)(GBLK * t), &deadlock);

    // ---- issue h(t) staging: 32 x global_load_lds, read-through no-allocate
#pragma unroll
    for (int it = 0; it < 32; ++it)
      __builtin_amdgcn_global_load_lds(
          (const GAS uint32_t*)(hsrc + it * 2048 + tid * 16),
          (LAS uint32_t*)(ldsA + it * 2048 + tid * 16), 16, 0, 17);
    __builtin_amdgcn_sched_barrier(0);

    // ---- build x(t) fragments from last iteration's prefetch (retired)
    half8 ax[4];
#pragma unroll
    for (int mt = 0; mt < 4; ++mt)
#pragma unroll
      for (int i = 0; i < 4; ++i) {
        ax[mt][i]     = (_Float16)xn0[mt][i];
        ax[mt][4 + i] = (_Float16)xn1[mt][i];
      }

    // ---- issue x(t+1) prefetch (12 VMEM insts per wave, exec-masked)
    {
      const int tx = (t + 1 < TT) ? (t + 1) : 0;
#pragma unroll
      for (int mt = 0; mt < 4; ++mt) {
        const float* xp = hist + (size_t)(crb + mt * 16 + l15) * (TT * II) + (size_t)tx * II;
        if (l4 == 0)      { xn0[mt] = *(const f32x4*)xp; xn1[mt] = *(const f32x4*)(xp + 4); }
        else if (l4 == 1) { xn0[mt] = *(const f32x4*)(xp + 8); }
      }
    }
    __builtin_amdgcn_sched_barrier(0);

    // outstanding: 32 staging + 12 x. vmcnt(28) -> 16 lo staging retired.
    asm volatile("s_waitcnt vmcnt(28)" ::: "memory");
    __builtin_amdgcn_s_barrier();
    __builtin_amdgcn_sched_barrier(0);

    f32x4 acc[4][3];
    f32x4 accin[4];
#pragma unroll
    for (int mt = 0; mt < 4; ++mt) {
      accin[mt] = (f32x4){0.f, 0.f, 0.f, 0.f};
#pragma unroll
      for (int nt = 0; nt < 3; ++nt) acc[mt][nt] = (f32x4){0.f, 0.f, 0.f, 0.f};
    }
    // x MFMAs (all mt; accin[2..3] carried into phase 2)
#pragma unroll
    for (int mt = 0; mt < 4; ++mt) {
      acc[mt][0] = __builtin_amdgcn_mfma_f32_16x16x32_f16(ax[mt], wih[0], acc[mt][0], 0, 0, 0);
      acc[mt][1] = __builtin_amdgcn_mfma_f32_16x16x32_f16(ax[mt], wih[1], acc[mt][1], 0, 0, 0);
      accin[mt]  = __builtin_amdgcn_mfma_f32_16x16x32_f16(ax[mt], wih[2], accin[mt], 0, 0, 0);
    }

    // ---- phase 1: rows 0-31 (mt = 0,1)
#pragma unroll
    for (int ks = 0; ks < 16; ++ks) {
      const int ko = (ks * 64 + l4 * 16) ^ ((l15 & 7) << 4);
      half8 a0 = *(const half8*)(ldsA + (0 * 16 + l15) * 1024 + ko);
      half8 a1 = *(const half8*)(ldsA + (1 * 16 + l15) * 1024 + ko);
      half8 b0 = *(const half8*)(ldsW + (wv * 32 + 0 * 16 + l15) * 1024 + ko);
      half8 b1 = *(const half8*)(ldsW + (wv * 32 + 1 * 16 + l15) * 1024 + ko);
      acc[0][0] = __builtin_amdgcn_mfma_f32_16x16x32_f16(a0, b0, acc[0][0], 0, 0, 0);
      acc[0][1] = __builtin_amdgcn_mfma_f32_16x16x32_f16(a0, b1, acc[0][1], 0, 0, 0);
      acc[0][2] = __builtin_amdgcn_mfma_f32_16x16x32_f16(a0, wn[ks], acc[0][2], 0, 0, 0);
      acc[1][0] = __builtin_amdgcn_mfma_f32_16x16x32_f16(a1, b0, acc[1][0], 0, 0, 0);
      acc[1][1] = __builtin_amdgcn_mfma_f32_16x16x32_f16(a1, b1, acc[1][1], 0, 0, 0);
      acc[1][2] = __builtin_amdgcn_mfma_f32_16x16x32_f16(a1, wn[ks], acc[1][2], 0, 0, 0);
    }

    // ---- gates + stores, rows 0-31 (write-through, pre-swizzled): 8 stores
#pragma unroll
    for (int mt = 0; mt < 2; ++mt)
#pragma unroll
      for (int q = 0; q < 4; ++q) {
        const int m = mt * 16 + l4 * 4 + q;
        const float r  = fast_sigmoid(acc[mt][0][q]);
        const float z  = fast_sigmoid(acc[mt][1][q]);
        const float n  = fast_tanh(accin[mt][q] + r * acc[mt][2][q]);
        const float hn = (1.0f - z) * n + z * hprev[mt][q];
        hprev[mt][q] = hn;
        const unsigned short hu = __builtin_bit_cast(unsigned short, (_Float16)hn);
        __hip_atomic_store(
            (unsigned short*)(hdst + m * 1024 + ((pcol * 2) ^ ((m & 7) << 4))),
            hu, __ATOMIC_RELAXED, __HIP_MEMORY_SCOPE_AGENT);
      }
    __builtin_amdgcn_sched_barrier(0);

    // outstanding <= 16 hi staging + 12 x + 8 stores. vmcnt(20) -> hi staged.
    asm volatile("s_waitcnt vmcnt(20)" ::: "memory");
    __builtin_amdgcn_s_barrier();
    __builtin_amdgcn_sched_barrier(0);

    // ---- phase 2: rows 32-63 (mt = 2,3)
#pragma unroll
    for (int ks = 0; ks < 16; ++ks) {
      const int ko = (ks * 64 + l4 * 16) ^ ((l15 & 7) << 4);
      half8 a2 = *(const half8*)(ldsA + (2 * 16 + l15) * 1024 + ko);
      half8 a3 = *(const half8*)(ldsA + (3 * 16 + l15) * 1024 + ko);
      half8 b0 = *(const half8*)(ldsW + (wv * 32 + 0 * 16 + l15) * 1024 + ko);
      half8 b1 = *(const half8*)(ldsW + (wv * 32 + 1 * 16 + l15) * 1024 + ko);
      acc[2][0] = __builtin_amdgcn_mfma_f32_16x16x32_f16(a2, b0, acc[2][0], 0, 0, 0);
      acc[2][1] = __builtin_amdgcn_mfma_f32_16x16x32_f16(a2, b1, acc[2][1], 0, 0, 0);
      acc[2][2] = __builtin_amdgcn_mfma_f32_16x16x32_f16(a2, wn[ks], acc[2][2], 0, 0, 0);
      acc[3][0] = __builtin_amdgcn_mfma_f32_16x16x32_f16(a3, b0, acc[3][0], 0, 0, 0);
      acc[3][1] = __builtin_amdgcn_mfma_f32_16x16x32_f16(a3, b1, acc[3][1], 0, 0, 0);
      acc[3][2] = __builtin_amdgcn_mfma_f32_16x16x32_f16(a3, wn[ks], acc[3][2], 0, 0, 0);
    }

    // ---- gates + stores, rows 32-63: 8 stores
#pragma unroll
    for (int mt = 2; mt < 4; ++mt)
#pragma unroll
      for (int q = 0; q < 4; ++q) {
        const int m = mt * 16 + l4 * 4 + q;
        const float r  = fast_sigmoid(acc[mt][0][q]);
        const float z  = fast_sigmoid(acc[mt][1][q]);
        const float n  = fast_tanh(accin[mt][q] + r * acc[mt][2][q]);
        const float hn = (1.0f - z) * n + z * hprev[mt][q];
        hprev[mt][q] = hn;
        const unsigned short hu = __builtin_bit_cast(unsigned short, (_Float16)hn);
        __hip_atomic_store(
            (unsigned short*)(hdst + m * 1024 + ((pcol * 2) ^ ((m & 7) << 4))),
            hu, __ATOMIC_RELAXED, __HIP_MEMORY_SCOPE_AGENT);
      }

    // ---- logits for step t-1 (LDS + regs only) — hides the store drain
    if (t > 0) {
      const int rr   = 2 * wv + (l >> 5);
      const int lrow = g * 4 + rr;
      const int row  = crb + lrow;
      float s = 0.0f;
#pragma unroll
      for (int c8 = 0; c8 < 4; ++c8) {
        half8 hv = *(const half8*)(ldsA + lrow * 1024 +
                                   ((l15 * 64 + c8 * 16) ^ ((lrow & 7) << 4)));
#pragma unroll
        for (int i = 0; i < 8; ++i) s += (float)hv[i] * wor[c8 * 8 + i];
      }
#pragma unroll
      for (int off = 1; off < 16; off <<= 1) s += __shfl_xor(s, off);
      if (l15 == 0) out[((size_t)row * TT + (t - 1)) * 2 + jj] = s + bo;
    }

    // ---- drain everything (stores + x prefetch), then post the flag
    asm volatile("s_waitcnt vmcnt(0)" ::: "memory");
    __builtin_amdgcn_s_barrier();
    if (tid == 0)
      __hip_atomic_fetch_add(bar, 1u, __ATOMIC_RELAXED, __HIP_MEMORY_SCOPE_AGENT);
  }

  // ---- epilogue: stage h(TT), logits for t = TT-1, h_final
  wait_flag(bar, (unsigned)(GBLK * TT), &deadlock);
  {
    const uint8_t* hsrc = ws + ((TT & 1) ? HBUF_B : 0) + (size_t)c * HTILE_B;
#pragma unroll
    for (int it = 0; it < 32; ++it)
      __builtin_amdgcn_global_load_lds(
          (const GAS uint32_t*)(hsrc + it * 2048 + tid * 16),
          (LAS uint32_t*)(ldsA + it * 2048 + tid * 16), 16, 0, 17);
    asm volatile("s_waitcnt vmcnt(0)" ::: "memory");
    __builtin_amdgcn_s_barrier();

    const int rr   = 2 * wv + (l >> 5);
    const int lrow = g * 4 + rr;
    const int row  = crb + lrow;
    float s = 0.0f;
#pragma unroll
    for (int c8 = 0; c8 < 4; ++c8) {
      half8 hv = *(const half8*)(ldsA + lrow * 1024 +
                                 ((l15 * 64 + c8 * 16) ^ ((lrow & 7) << 4)));
#pragma unroll
      for (int i = 0; i < 8; ++i) s += (float)hv[i] * wor[c8 * 8 + i];
    }
#pragma unroll
    for (int off = 1; off < 16; off <<= 1) s += __shfl_xor(s, off);
    if (l15 == 0) out[((size_t)row * TT + (TT - 1)) * 2 + jj] = s + bo;
  }

  // ---- h_final from fp32 carried state
#pragma unroll
  for (int mt = 0; mt < 4; ++mt)
#pragma unroll
    for (int q = 0; q < 4; ++q) {
      const int m = mt * 16 + l4 * 4 + q;
      out[(size_t)TB * TT * 2 + (size_t)(crb + m) * HH + pcol] = hprev[mt][q];
    }
}

extern "C" void kernel_launch(void* const* d_in, const int* in_sizes, int n_in,
                              void* d_out, int out_size, void* d_ws, size_t ws_size,
                              hipStream_t stream) {
  (void)in_sizes; (void)n_in; (void)out_size;
  if (ws_size < WS_USED) return;

  const float* hist  = (const float*)d_in[0];
  const float* w_ih  = (const float*)d_in[1];
  const float* w_hh  = (const float*)d_in[2];
  const float* w_out = (const float*)d_in[3];
  const float* b_out = (const float*)d_in[4];
  float* out = (float*)d_out;
  uint8_t* ws = (uint8_t*)d_ws;

  hipFuncSetAttribute((const void*)gru_persistent,
                      hipFuncAttributeMaxDynamicSharedMemorySize, LDSB);
  hipMemsetAsync(d_ws, 0, WS_USED, stream);   // h0 = 0, flag counters

  void* args[] = {(void*)&hist, (void*)&w_ih, (void*)&w_hh, (void*)&w_out,
                  (void*)&b_out, (void*)&out, (void*)&ws};
  hipError_t e = hipLaunchCooperativeKernel((const void*)gru_persistent,
                                            dim3(NB), dim3(NT), args,
                                            (unsigned)LDSB, stream);
  if (e != hipSuccess) {
    // Fallback: plain launch. 256 blocks at 1/CU on 256 CUs co-reside; the
    // flag spin has a deadlock bail-out so this cannot hang.
    gru_persistent<<<dim3(NB), dim3(NT), LDSB, stream>>>(
        hist, w_ih, w_hh, w_out, b_out, out, ws);
  }
}

// Round 8
// 7626.775 us; speedup vs baseline: 1.9955x; 1.6612x over previous
//
#include <hip/hip_runtime.h>
#include <stdint.h>

// GRU scan, persistent cooperative kernel, round 8.
// Round 7 coherence discipline (write-through h stores RELAXED/AGENT, aux=17
// read-through staging, relaxed flags, no fences, x prefetch, counted vmcnt) +
//  - NT=256: 4 waves -> all 4 SIMDs busy (round 7 left half the CU idle)
//  - 32 clusters x 32 rows x 8 blocks, block owns 64 cols: halves the staged
//    A-tile (32KB/block, 8MB/step LIC reads) and producers per flag
//  - ALL W_hh gate slices in registers (wr/wz/wn, 192 VGPR/wave, static idx);
//    LDS = 32KB A-tile only, no W fill, no B-side ds_reads
//  - per-producer flag words in one line (no atomic RMW contention); consumers
//    poll 8 words lane-parallel + __all

#define NB 256
#define NT 256
#define TB 1024
#define TT 2048
#define II 12
#define HH 512
#define NCL 32
#define GBLK 8
#define ROWS 32

#define HTILE_B (ROWS * HH * 2)               // 32 KiB per cluster per buffer
#define HBUF_B  ((size_t)NCL * HTILE_B)       // 1 MiB per buffer
#define BAR_OFF ((size_t)2 * HBUF_B)
#define WS_USED (BAR_OFF + NCL * 128)

#define LDSB (ROWS * 1024)                    // 32 KiB A-tile

#define GAS __attribute__((address_space(1)))
#define LAS __attribute__((address_space(3)))

typedef _Float16 half8 __attribute__((ext_vector_type(8)));
typedef float    f32x4 __attribute__((ext_vector_type(4)));

static __device__ __forceinline__ float fast_sigmoid(float x) {
  float e = exp2f(-1.44269504f * x);
  return __builtin_amdgcn_rcpf(1.0f + e);
}
static __device__ __forceinline__ float fast_tanh(float x) {
  float e = exp2f(2.88539008f * x);           // exp(2x)
  return 1.0f - 2.0f * __builtin_amdgcn_rcpf(1.0f + e);
}

// Poll 8 per-producer flag words (one 32B span) lane-parallel, relaxed.
static __device__ __forceinline__ void wait_flags8(unsigned* f, unsigned tgt,
                                                   int* dead) {
  const int l = threadIdx.x & 63;
  long spin = 0;
  for (;;) {
    unsigned v = __hip_atomic_load(f + (l & 7), __ATOMIC_RELAXED,
                                   __HIP_MEMORY_SCOPE_AGENT);
    if (__all(v >= tgt)) break;
    if (++spin > (1L << 24)) { *dead = 1; break; }
  }
}

__global__ void __launch_bounds__(NT, 1)
gru_persistent(const float* __restrict__ hist,
               const float* __restrict__ w_ih,
               const float* __restrict__ w_hh,
               const float* __restrict__ w_out,
               const float* __restrict__ b_out,
               float* __restrict__ out,
               uint8_t* __restrict__ ws)
{
  extern __shared__ char smem[];
  char* ldsA = smem;
  const int bid = blockIdx.x;
  const int c   = bid & 31;          // cluster (32)
  const int g   = bid >> 5;          // block within cluster (8)
  const int tid = threadIdx.x;
  const int w   = tid >> 6;          // wave 0..3 -> col-tile
  const int l   = tid & 63;
  const int l15 = l & 15;
  const int l4  = l >> 4;
  const int crb = c * ROWS;
  unsigned* flags = (unsigned*)(ws + BAR_OFF) + c * 32;  // 128B line / cluster

  const int col0 = g * 64 + w * 16;  // wave's 16 output cols

  // ---- W_hh register B-fragments for r,z,n (16 K-slices each, static idx)
  half8 wr[16], wz[16], wn[16];
#pragma unroll
  for (int ks = 0; ks < 16; ++ks) {
    const size_t Rr = (size_t)(0 * HH + col0 + l15) * HH + ks * 32 + l4 * 8;
    const size_t Rz = (size_t)(1 * HH + col0 + l15) * HH + ks * 32 + l4 * 8;
    const size_t Rn = (size_t)(2 * HH + col0 + l15) * HH + ks * 32 + l4 * 8;
#pragma unroll
    for (int i = 0; i < 8; ++i) {
      wr[ks][i] = (_Float16)w_hh[Rr + i];
      wz[ks][i] = (_Float16)w_hh[Rz + i];
      wn[ks][i] = (_Float16)w_hh[Rn + i];
    }
  }

  // ---- w_ih register B-fragments (K window = x cols 0..31)
  half8 wih[3];
#pragma unroll
  for (int gt = 0; gt < 3; ++gt) {
    const int R = gt * HH + col0 + l15;
#pragma unroll
    for (int i = 0; i < 8; ++i) {
      const int k = l4 * 8 + i;
      wih[gt][i] = (_Float16)((k < II) ? w_ih[R * II + k] : 0.0f);
    }
  }

  // ---- w_out in registers (logits: wave w handles local row g*4+w... see below)
  const int jj = (l >> 4) & 1;
  float wor[32];
#pragma unroll
  for (int i = 0; i < 32; ++i) wor[i] = w_out[jj * HH + l15 * 32 + i];
  const float bo = b_out[jj];

  float hprev[2][4];
#pragma unroll
  for (int mt = 0; mt < 2; ++mt)
#pragma unroll
    for (int q = 0; q < 4; ++q) hprev[mt][q] = 0.0f;

  const int pcol = col0 + l15;
  int deadlock = 0;

  // ---- x prologue: prefetch x(0)
  f32x4 xn0[2], xn1[2];
#pragma unroll
  for (int mt = 0; mt < 2; ++mt) {
    xn0[mt] = (f32x4){0.f, 0.f, 0.f, 0.f};
    xn1[mt] = (f32x4){0.f, 0.f, 0.f, 0.f};
    const float* xp = hist + (size_t)(crb + mt * 16 + l15) * (TT * II);
    if (l4 == 0)      { xn0[mt] = *(const f32x4*)xp; xn1[mt] = *(const f32x4*)(xp + 4); }
    else if (l4 == 1) { xn0[mt] = *(const f32x4*)(xp + 8); }
  }

  for (int t = 0; t < TT; ++t) {
    const uint8_t* hsrc = ws + ((t & 1) ? HBUF_B : 0) + (size_t)c * HTILE_B;
    uint8_t*       hdst = ws + ((t & 1) ? 0 : HBUF_B) + (size_t)c * HTILE_B;

    if (t > 0) wait_flags8(flags, (unsigned)t, &deadlock);

    // ---- issue h(t) staging: 8 insts/wave (wave w covers rows it*4+w)
#pragma unroll
    for (int it = 0; it < 8; ++it)
      __builtin_amdgcn_global_load_lds(
          (const GAS uint32_t*)(hsrc + it * 4096 + tid * 16),
          (LAS uint32_t*)(ldsA + it * 4096 + tid * 16), 16, 0, 17);
    __builtin_amdgcn_sched_barrier(0);

    // ---- build x(t) fragments from last prefetch; issue x(t+1) prefetch
    half8 ax[2];
#pragma unroll
    for (int mt = 0; mt < 2; ++mt)
#pragma unroll
      for (int i = 0; i < 4; ++i) {
        ax[mt][i]     = (_Float16)xn0[mt][i];
        ax[mt][4 + i] = (_Float16)xn1[mt][i];
      }
    {
      const int tx = (t + 1 < TT) ? (t + 1) : 0;
#pragma unroll
      for (int mt = 0; mt < 2; ++mt) {
        const float* xp = hist + (size_t)(crb + mt * 16 + l15) * (TT * II) + (size_t)tx * II;
        if (l4 == 0)      { xn0[mt] = *(const f32x4*)xp; xn1[mt] = *(const f32x4*)(xp + 4); }
        else if (l4 == 1) { xn0[mt] = *(const f32x4*)(xp + 8); }
      }
    }
    __builtin_amdgcn_sched_barrier(0);

    // outstanding/wave: 8 staging + 6 x. vmcnt(10) -> lo (rows 0-15) staged.
    asm volatile("s_waitcnt vmcnt(10)" ::: "memory");
    __builtin_amdgcn_s_barrier();
    __builtin_amdgcn_sched_barrier(0);

    f32x4 acc0, acc1, acc2, accin;

    // ======== phase 1: rows 0-15 (mt=0) ========
    acc0 = (f32x4){0.f, 0.f, 0.f, 0.f};
    acc1 = acc0; acc2 = acc0;
    accin = __builtin_amdgcn_mfma_f32_16x16x32_f16(ax[0], wih[2],
              (f32x4){0.f, 0.f, 0.f, 0.f}, 0, 0, 0);
    acc0 = __builtin_amdgcn_mfma_f32_16x16x32_f16(ax[0], wih[0], acc0, 0, 0, 0);
    acc1 = __builtin_amdgcn_mfma_f32_16x16x32_f16(ax[0], wih[1], acc1, 0, 0, 0);
#pragma unroll
    for (int ks = 0; ks < 16; ++ks) {
      const int ko = (ks * 64 + l4 * 16) ^ ((l15 & 7) << 4);
      half8 a = *(const half8*)(ldsA + l15 * 1024 + ko);
      acc0 = __builtin_amdgcn_mfma_f32_16x16x32_f16(a, wr[ks], acc0, 0, 0, 0);
      acc1 = __builtin_amdgcn_mfma_f32_16x16x32_f16(a, wz[ks], acc1, 0, 0, 0);
      acc2 = __builtin_amdgcn_mfma_f32_16x16x32_f16(a, wn[ks], acc2, 0, 0, 0);
    }
#pragma unroll
    for (int q = 0; q < 4; ++q) {
      const int m = l4 * 4 + q;                       // rows 0-15
      const float r  = fast_sigmoid(acc0[q]);
      const float z  = fast_sigmoid(acc1[q]);
      const float n  = fast_tanh(accin[q] + r * acc2[q]);
      const float hn = (1.0f - z) * n + z * hprev[0][q];
      hprev[0][q] = hn;
      const unsigned short hu = __builtin_bit_cast(unsigned short, (_Float16)hn);
      __hip_atomic_store(
          (unsigned short*)(hdst + m * 1024 + ((pcol * 2) ^ ((m & 7) << 4))),
          hu, __ATOMIC_RELAXED, __HIP_MEMORY_SCOPE_AGENT);
    }
    __builtin_amdgcn_sched_barrier(0);

    // outstanding: 4 hi staging + 6 x + 4 stores. vmcnt(10) -> hi staged.
    asm volatile("s_waitcnt vmcnt(10)" ::: "memory");
    __builtin_amdgcn_s_barrier();
    __builtin_amdgcn_sched_barrier(0);

    // ======== phase 2: rows 16-31 (mt=1) ========
    acc0 = (f32x4){0.f, 0.f, 0.f, 0.f};
    acc1 = acc0; acc2 = acc0;
    accin = __builtin_amdgcn_mfma_f32_16x16x32_f16(ax[1], wih[2],
              (f32x4){0.f, 0.f, 0.f, 0.f}, 0, 0, 0);
    acc0 = __builtin_amdgcn_mfma_f32_16x16x32_f16(ax[1], wih[0], acc0, 0, 0, 0);
    acc1 = __builtin_amdgcn_mfma_f32_16x16x32_f16(ax[1], wih[1], acc1, 0, 0, 0);
#pragma unroll
    for (int ks = 0; ks < 16; ++ks) {
      const int ko = (ks * 64 + l4 * 16) ^ ((l15 & 7) << 4);
      half8 a = *(const half8*)(ldsA + (16 + l15) * 1024 + ko);
      acc0 = __builtin_amdgcn_mfma_f32_16x16x32_f16(a, wr[ks], acc0, 0, 0, 0);
      acc1 = __builtin_amdgcn_mfma_f32_16x16x32_f16(a, wz[ks], acc1, 0, 0, 0);
      acc2 = __builtin_amdgcn_mfma_f32_16x16x32_f16(a, wn[ks], acc2, 0, 0, 0);
    }
#pragma unroll
    for (int q = 0; q < 4; ++q) {
      const int m = 16 + l4 * 4 + q;                  // rows 16-31
      const float r  = fast_sigmoid(acc0[q]);
      const float z  = fast_sigmoid(acc1[q]);
      const float n  = fast_tanh(accin[q] + r * acc2[q]);
      const float hn = (1.0f - z) * n + z * hprev[1][q];
      hprev[1][q] = hn;
      const unsigned short hu = __builtin_bit_cast(unsigned short, (_Float16)hn);
      __hip_atomic_store(
          (unsigned short*)(hdst + m * 1024 + ((pcol * 2) ^ ((m & 7) << 4))),
          hu, __ATOMIC_RELAXED, __HIP_MEMORY_SCOPE_AGENT);
    }

    // ---- logits for step t-1 from ldsA = h(t); block's rows g*4..g*4+3,
    //      wave w does local row g*4+w? g in [0,8) -> g*4+w in [0,31] ✓
    if (t > 0) {
      const int lr  = ((g * 4 + w) & 31);
      const int row = crb + lr;
      float s = 0.0f;
#pragma unroll
      for (int c8 = 0; c8 < 4; ++c8) {
        half8 hv = *(const half8*)(ldsA + lr * 1024 +
                                   ((l15 * 64 + c8 * 16) ^ ((lr & 7) << 4)));
#pragma unroll
        for (int i = 0; i < 8; ++i) s += (float)hv[i] * wor[c8 * 8 + i];
      }
#pragma unroll
      for (int off = 1; off < 16; off <<= 1) s += __shfl_xor(s, off);
      if (l15 == 0 && l < 32) out[((size_t)row * TT + (t - 1)) * 2 + jj] = s + bo;
    }

    // ---- drain stores (+x), post per-producer flag (plain write-through)
    asm volatile("s_waitcnt vmcnt(0)" ::: "memory");
    __builtin_amdgcn_s_barrier();
    if (tid == 0)
      __hip_atomic_store(flags + g, (unsigned)(t + 1), __ATOMIC_RELAXED,
                         __HIP_MEMORY_SCOPE_AGENT);
  }

  // ---- epilogue: stage h(TT), logits for t = TT-1, h_final
  wait_flags8(flags, (unsigned)TT, &deadlock);
  {
    const uint8_t* hsrc = ws + ((TT & 1) ? HBUF_B : 0) + (size_t)c * HTILE_B;
#pragma unroll
    for (int it = 0; it < 8; ++it)
      __builtin_amdgcn_global_load_lds(
          (const GAS uint32_t*)(hsrc + it * 4096 + tid * 16),
          (LAS uint32_t*)(ldsA + it * 4096 + tid * 16), 16, 0, 17);
    asm volatile("s_waitcnt vmcnt(0)" ::: "memory");
    __builtin_amdgcn_s_barrier();

    const int lr  = ((g * 4 + w) & 31);
    const int row = crb + lr;
    float s = 0.0f;
#pragma unroll
    for (int c8 = 0; c8 < 4; ++c8) {
      half8 hv = *(const half8*)(ldsA + lr * 1024 +
                                 ((l15 * 64 + c8 * 16) ^ ((lr & 7) << 4)));
#pragma unroll
      for (int i = 0; i < 8; ++i) s += (float)hv[i] * wor[c8 * 8 + i];
    }
#pragma unroll
    for (int off = 1; off < 16; off <<= 1) s += __shfl_xor(s, off);
    if (l15 == 0 && l < 32) out[((size_t)row * TT + (TT - 1)) * 2 + jj] = s + bo;
  }

  // ---- h_final from fp32 carried state
#pragma unroll
  for (int mt = 0; mt < 2; ++mt)
#pragma unroll
    for (int q = 0; q < 4; ++q) {
      const int m = mt * 16 + l4 * 4 + q;
      out[(size_t)TB * TT * 2 + (size_t)(crb + m) * HH + pcol] = hprev[mt][q];
    }
}

extern "C" void kernel_launch(void* const* d_in, const int* in_sizes, int n_in,
                              void* d_out, int out_size, void* d_ws, size_t ws_size,
                              hipStream_t stream) {
  (void)in_sizes; (void)n_in; (void)out_size;
  if (ws_size < WS_USED) return;

  const float* hist  = (const float*)d_in[0];
  const float* w_ih  = (const float*)d_in[1];
  const float* w_hh  = (const float*)d_in[2];
  const float* w_out = (const float*)d_in[3];
  const float* b_out = (const float*)d_in[4];
  float* out = (float*)d_out;
  uint8_t* ws = (uint8_t*)d_ws;

  hipMemsetAsync(d_ws, 0, WS_USED, stream);   // h0 = 0, flag words

  void* args[] = {(void*)&hist, (void*)&w_ih, (void*)&w_hh, (void*)&w_out,
                  (void*)&b_out, (void*)&out, (void*)&ws};
  hipError_t e = hipLaunchCooperativeKernel((const void*)gru_persistent,
                                            dim3(NB), dim3(NT), args,
                                            (unsigned)LDSB, stream);
  if (e != hipSuccess) {
    // Fallback: plain launch. 256 blocks at 1/CU on 256 CUs co-reside; the
    // flag spin has a deadlock bail-out so this cannot hang.
    gru_persistent<<<dim3(NB), dim3(NT), LDSB, stream>>>(
        hist, w_ih, w_hh, w_out, b_out, out, ws);
  }
}